// Round 18
// baseline (103.334 us; speedup 1.0000x reference)
//
#include <hip/hip_runtime.h>
#include <hip/hip_bf16.h>

typedef _Float16 half8 __attribute__((ext_vector_type(8)));
typedef _Float16 f16x8 __attribute__((ext_vector_type(8)));
typedef __bf16 bf16x2v __attribute__((ext_vector_type(2)));
typedef __bf16 bf16x8 __attribute__((ext_vector_type(8)));
typedef float f32x16 __attribute__((ext_vector_type(16)));
typedef unsigned uint2v __attribute__((ext_vector_type(2)));

#define NPIX 16384      // H*W
#define NPOOL 4096      // pooled N
#define BN 32768        // B*N
#define KSPLIT 8
#define CHUNK 512       // NPOOL/KSPLIT
#define LOG2E 1.44269504088896340736f

__device__ inline f32x16 mfma16(half8 a, half8 b, f32x16 c) {
  return __builtin_amdgcn_mfma_f32_32x32x16_f16(a, b, c, 0, 0, 0);
}
__device__ inline f32x16 mfma16b(bf16x8 a, bf16x8 b, f32x16 c) {
  return __builtin_amdgcn_mfma_f32_32x32x16_bf16(a, b, c, 0, 0, 0);
}
__device__ inline float fast_exp2(float x) {
#if __has_builtin(__builtin_amdgcn_exp2f)
  return __builtin_amdgcn_exp2f(x);      // raw v_exp_f32 (1 inst, <=1 ulp)
#else
  return exp2f(x);
#endif
}

// ---- K1 (fused prep): theta f16 [BN][8]*log2e; phiT f16 [b][M][8]; gT bf16 [b][64][M]
__global__ __launch_bounds__(256) void prep_kernel(
    const float* __restrict__ x,
    const float* __restrict__ w_theta, const float* __restrict__ b_theta,
    const float* __restrict__ w_phi, const float* __restrict__ b_phi,
    const float* __restrict__ w_g, const float* __restrict__ b_g,
    _Float16* __restrict__ qf, _Float16* __restrict__ phiT,
    __bf16* __restrict__ gT) {
  __shared__ float xs[64][256];
  int bid = blockIdx.x;
  int oh = bid & 1;
  int pr = (bid >> 1) & 63;
  int b  = bid >> 7;
  int t = threadIdx.x;

  const float* xb = x + (size_t)b * 64 * NPIX + pr * 256;
#pragma unroll 8
  for (int c = 0; c < 64; c++) xs[c][t] = xb[(size_t)c * NPIX + t];
  __syncthreads();

  if (oh == 0) {
    float acc[8];
#pragma unroll
    for (int j = 0; j < 8; j++) acc[j] = b_theta[j];
#pragma unroll 4
    for (int c = 0; c < 64; c++) {
      float xv = xs[c][t];
#pragma unroll
      for (int j = 0; j < 8; j++) acc[j] += xv * w_theta[j * 64 + c];
    }
    half8 h;
#pragma unroll
    for (int j = 0; j < 8; j++) h[j] = (_Float16)(acc[j] * LOG2E);
    *(half8*)(qf + ((size_t)b * NPIX + pr * 256 + t) * 8) = h;
  }

  int pos = t & 63;
  int ocg = t >> 6;
  int oc0 = oh * 36 + ocg * 9;
  const float* wrow[9];
  float a0[9], a1[9], a2[9], a3[9];
#pragma unroll
  for (int j = 0; j < 9; j++) {
    int oc = oc0 + j;
    float bv;
    if (oc < 64) { wrow[j] = w_g + oc * 64; bv = b_g[oc]; }
    else         { wrow[j] = w_phi + (oc - 64) * 64; bv = b_phi[oc - 64]; }
    a0[j] = bv; a1[j] = bv; a2[j] = bv; a3[j] = bv;
  }
#pragma unroll 4
  for (int c = 0; c < 64; c++) {
    float2 lo = *(const float2*)&xs[c][2 * pos];
    float2 hi = *(const float2*)&xs[c][128 + 2 * pos];
#pragma unroll
    for (int j = 0; j < 9; j++) {
      float wv = wrow[j][c];
      a0[j] += wv * lo.x;
      a1[j] += wv * lo.y;
      a2[j] += wv * hi.x;
      a3[j] += wv * hi.y;
    }
  }
  int m = pr * 64 + pos;
#pragma unroll
  for (int j = 0; j < 9; j++) {
    int oc = oc0 + j;
    float v = fmaxf(fmaxf(a0[j], a1[j]), fmaxf(a2[j], a3[j]));
    if (oc < 64) gT[((size_t)b * 64 + oc) * NPOOL + m] = (__bf16)v;
    else         phiT[((size_t)b * NPOOL + m) * 8 + (oc - 64)] = (_Float16)v;
  }
}

// ---- K2: flash attention; NO LDS, NO barriers — g read direct via L1/L2 ----
// gT (1 MB/batch) is L2-resident; per-frame working set (64 rows x 64B) L1-fits.
// grid = b(2) x qt(128) x kc(8) = 2048 blocks; 4 independent waves x 32 queries
__global__ __launch_bounds__(256, 4) void attn_kernel(
    const _Float16* __restrict__ qf, const _Float16* __restrict__ phiT,
    const __bf16* __restrict__ gT,
    float* __restrict__ part_l, _Float16* __restrict__ part_o) {
  int bx = blockIdx.x;
  int kc = bx & (KSPLIT - 1);
  int qt = (bx >> 3) & 127;
  int b  = bx >> 10;
  int tid = threadIdx.x;
  int lane = tid & 63;
  int w = tid >> 6;
  int q = lane & 31, hi = lane >> 5;
  int qg0 = qt * 128 + w * 32;
  size_t qrow = (size_t)b * NPIX + qg0 + q;

  half8 qfrag = {0, 0, 0, 0, 0, 0, 0, 0};
  if (!hi) qfrag = *(const half8*)(qf + qrow * 8);

  f32x16 oacc0, oacc1;
#pragma unroll
  for (int i = 0; i < 16; i++) { oacc0[i] = 0.f; oacc1[i] = 0.f; }
  float lsum = 0.f;

  int kb0 = kc * CHUNK;
  // per-lane g row pointers: rows q and q+32; fragment at [key + 8*sread]
  const __bf16* gag0 = gT + ((size_t)b * 64 + q) * NPOOL;
  const __bf16* gag1 = gag0 + (size_t)32 * NPOOL;
  const _Float16* phb = phiT + (size_t)b * NPOOL * 8;

#pragma unroll 2
  for (int step = 0; step < CHUNK / 64; ++step) {
    int kbb = kb0 + step * 64;
    half8 aphi0 = {0, 0, 0, 0, 0, 0, 0, 0}, aphi1 = aphi0;
    if (!hi) {
      aphi0 = *(const half8*)(phb + (size_t)(kbb + q) * 8);
      aphi1 = *(const half8*)(phb + (size_t)(kbb + 32 + q) * 8);
    }
#pragma unroll
    for (int sub = 0; sub < 2; ++sub) {
      half8 aphi = sub ? aphi1 : aphi0;
      f32x16 sacc;
#pragma unroll
      for (int i = 0; i < 16; i++) sacc[i] = 0.f;    // no shift needed (bf16 P)
      sacc = mfma16(aphi, qfrag, sacc);
      float p[16];
#pragma unroll
      for (int i = 0; i < 16; i++) p[i] = fast_exp2(sacc[i]);
      lsum += (((p[0] + p[1]) + (p[2] + p[3])) + ((p[4] + p[5]) + (p[6] + p[7]))) +
              (((p[8] + p[9]) + (p[10] + p[11])) + ((p[12] + p[13]) + (p[14] + p[15])));
#pragma unroll
      for (int halfk = 0; halfk < 2; ++halfk) {
        int pb = halfk * 8;
        bf16x2v t0 = {(__bf16)p[pb + 0], (__bf16)p[pb + 1]};
        bf16x2v t1 = {(__bf16)p[pb + 2], (__bf16)p[pb + 3]};
        bf16x2v t2 = {(__bf16)p[pb + 4], (__bf16)p[pb + 5]};
        bf16x2v t3 = {(__bf16)p[pb + 6], (__bf16)p[pb + 7]};
        unsigned A0 = __builtin_bit_cast(unsigned, t0);
        unsigned A1 = __builtin_bit_cast(unsigned, t1);
        unsigned B0 = __builtin_bit_cast(unsigned, t2);
        unsigned B1 = __builtin_bit_cast(unsigned, t3);
        union { unsigned u[4]; bf16x8 h; } pf;
#if __has_builtin(__builtin_amdgcn_permlane32_swap)
        uint2v r0 = __builtin_amdgcn_permlane32_swap(A0, B0, false, false);
        uint2v r1 = __builtin_amdgcn_permlane32_swap(A1, B1, false, false);
        pf.u[0] = r0[0]; pf.u[1] = r1[0]; pf.u[2] = r0[1]; pf.u[3] = r1[1];
#else
        unsigned xA0 = __shfl_xor(A0, 32), xA1 = __shfl_xor(A1, 32);
        unsigned xB0 = __shfl_xor(B0, 32), xB1 = __shfl_xor(B1, 32);
        pf.u[0] = hi ? xB0 : A0;
        pf.u[1] = hi ? xB1 : A1;
        pf.u[2] = hi ? B0 : xA0;
        pf.u[3] = hi ? B1 : xA1;
#endif
        int koff = kbb + 8 * (sub * 4 + halfk * 2 + hi);   // 8-key fragment base
        __builtin_amdgcn_s_setprio(1);
        bf16x8 ag0 = *(const bf16x8*)(gag0 + koff);        // L1/L2 direct
        oacc0 = mfma16b(ag0, pf.h, oacc0);
        bf16x8 ag1 = *(const bf16x8*)(gag1 + koff);
        oacc1 = mfma16b(ag1, pf.h, oacc1);
        __builtin_amdgcn_s_setprio(0);
      }
    }
  }
  lsum += __shfl_xor(lsum, 32);          // chunk-total l (both half-lanes)
  float rl = 1.0f / lsum;
  if (!hi) part_l[(size_t)kc * BN + qrow] = lsum;
  // part_o f16 layout [kc][b][n][64] holds NORMALIZED o/l; 8B packed stores
  _Float16* po = part_o + (((size_t)(kc * 2 + b) * NPIX) + qg0 + q) * 64;
#pragma unroll
  for (int ct = 0; ct < 2; ++ct) {
#pragma unroll
    for (int g = 0; g < 4; ++g) {
      float v0 = (ct ? oacc1[4 * g + 0] : oacc0[4 * g + 0]) * rl;
      float v1 = (ct ? oacc1[4 * g + 1] : oacc0[4 * g + 1]) * rl;
      float v2 = (ct ? oacc1[4 * g + 2] : oacc0[4 * g + 2]) * rl;
      float v3 = (ct ? oacc1[4 * g + 3] : oacc0[4 * g + 3]) * rl;
      uint2v u;
      u[0] = __builtin_bit_cast(unsigned, __builtin_amdgcn_cvt_pkrtz(v0, v1));
      u[1] = __builtin_bit_cast(unsigned, __builtin_amdgcn_cvt_pkrtz(v2, v3));
      *(uint2v*)(po + 32 * ct + 8 * g + 4 * hi) = u;   // ch = (r&3)+8g+4hi+32ct
    }
  }
}

// ---- K3: l-weighted combine + residual epilogue ----
__global__ __launch_bounds__(256) void reduce_kernel(
    const float* __restrict__ part_l, const _Float16* __restrict__ part_o,
    const float* __restrict__ x, const float* __restrict__ sig,
    float* __restrict__ out) {
  int t = threadIdx.x;
  int cg = t >> 6;                       // 0..3 -> channels cg*16..+15
  int qi = blockIdx.x * 64 + (t & 63);
  int b = qi >> 14, n = qi & (NPIX - 1);
  float lv[KSPLIT], L = 0.f;
#pragma unroll
  for (int kc = 0; kc < KSPLIT; kc++) {
    lv[kc] = part_l[(size_t)kc * BN + qi];
    L += lv[kc];
  }
  float o16[16];
#pragma unroll
  for (int j = 0; j < 16; j++) o16[j] = 0.f;
#pragma unroll
  for (int kc = 0; kc < KSPLIT; kc++) {
    const _Float16* po = part_o + (((size_t)(kc * 2 + b) * NPIX) + n) * 64 + cg * 16;
    f16x8 v0 = *(const f16x8*)po;
    f16x8 v1 = *(const f16x8*)(po + 8);
    float wv = lv[kc];
#pragma unroll
    for (int j = 0; j < 8; j++) {
      o16[j]     += wv * (float)v0[j];
      o16[8 + j] += wv * (float)v1[j];
    }
  }
  float scale = sig[0] / L;
#pragma unroll
  for (int j = 0; j < 16; j++) {
    int c = cg * 16 + j;
    size_t idx = ((size_t)b * 64 + c) * NPIX + n;
    out[idx] = x[idx] + scale * o16[j];
  }
}

extern "C" void kernel_launch(void* const* d_in, const int* in_sizes, int n_in,
                              void* d_out, int out_size, void* d_ws, size_t ws_size,
                              hipStream_t stream) {
  const float* x       = (const float*)d_in[0];
  const float* w_theta = (const float*)d_in[1];
  const float* b_theta = (const float*)d_in[2];
  const float* w_phi   = (const float*)d_in[3];
  const float* b_phi   = (const float*)d_in[4];
  const float* w_g     = (const float*)d_in[5];
  const float* b_g     = (const float*)d_in[6];
  const float* sigma   = (const float*)d_in[7];
  float* out = (float*)d_out;

  // Workspace layout (bytes):
  //   qf     @ 0        : BN*8*2              = 524288
  //   phiT   @ 524288   : 2*NPOOL*8*2         = 131072
  //   gT     @ 655360   : 2*64*NPOOL*2        = 1048576  (bf16)
  //   part_l @ 1703936  : KSPLIT*BN*4         = 1048576
  //   part_o @ 2752512  : KSPLIT*2*NPIX*64*2  = 33554432   (total ~36.3 MB)
  char* ws = (char*)d_ws;
  _Float16* qf     = (_Float16*)ws;
  _Float16* phiT   = (_Float16*)(ws + 524288);
  __bf16*   gT     = (__bf16*)(ws + 655360);
  float*    part_l = (float*)(ws + 1703936);
  _Float16* part_o = (_Float16*)(ws + 2752512);

  prep_kernel<<<256, 256, 0, stream>>>(x, w_theta, b_theta, w_phi, b_phi,
                                       w_g, b_g, qf, phiT, gT);
  attn_kernel<<<2 * 128 * KSPLIT, 256, 0, stream>>>(qf, phiT, gT,
                                                    part_l, part_o);
  reduce_kernel<<<512, 256, 0, stream>>>(part_l, part_o, x, sigma, out);
}

// Round 19
// 68.006 us; speedup vs baseline: 1.5195x; 1.5195x over previous
//
#include <hip/hip_runtime.h>
#include <hip/hip_bf16.h>

typedef _Float16 half8 __attribute__((ext_vector_type(8)));
typedef _Float16 f16x8 __attribute__((ext_vector_type(8)));
typedef __bf16 bf16x8 __attribute__((ext_vector_type(8)));
typedef float f32x16 __attribute__((ext_vector_type(16)));
typedef unsigned uint2v __attribute__((ext_vector_type(2)));

#define NPIX 16384      // H*W
#define NPOOL 4096      // pooled N
#define BN 32768        // B*N
#define KSPLIT 8
#define CHUNK 512       // NPOOL/KSPLIT
#define NSTEP 4         // CHUNK/128 (128 keys per barrier frame)
#define LOG2E 1.44269504088896340736f

__device__ inline f32x16 mfma16(half8 a, half8 b, f32x16 c) {
  return __builtin_amdgcn_mfma_f32_32x32x16_f16(a, b, c, 0, 0, 0);
}
__device__ inline f32x16 mfma16b(bf16x8 a, bf16x8 b, f32x16 c) {
  return __builtin_amdgcn_mfma_f32_32x32x16_bf16(a, b, c, 0, 0, 0);
}
__device__ inline float fast_exp2(float x) {
#if __has_builtin(__builtin_amdgcn_exp2f)
  return __builtin_amdgcn_exp2f(x);      // raw v_exp_f32 (1 inst, <=1 ulp)
#else
  return exp2f(x);
#endif
}
// f32 pair -> packed 2x bf16 (RNE) in one instruction
__device__ inline unsigned cvt_pk_bf16(float lo, float hi) {
  unsigned r;
  asm("v_cvt_pk_bf16_f32 %0, %1, %2" : "=v"(r) : "v"(lo), "v"(hi));
  return r;
}

// ---- K1 (fused prep): theta f16 [BN][8]*log2e; phiT f16 [b][M][8]; gT bf16 [b][64][M]
__global__ __launch_bounds__(256) void prep_kernel(
    const float* __restrict__ x,
    const float* __restrict__ w_theta, const float* __restrict__ b_theta,
    const float* __restrict__ w_phi, const float* __restrict__ b_phi,
    const float* __restrict__ w_g, const float* __restrict__ b_g,
    _Float16* __restrict__ qf, _Float16* __restrict__ phiT,
    __bf16* __restrict__ gT) {
  __shared__ float xs[64][256];
  int bid = blockIdx.x;
  int oh = bid & 1;
  int pr = (bid >> 1) & 63;
  int b  = bid >> 7;
  int t = threadIdx.x;

  const float* xb = x + (size_t)b * 64 * NPIX + pr * 256;
#pragma unroll 8
  for (int c = 0; c < 64; c++) xs[c][t] = xb[(size_t)c * NPIX + t];
  __syncthreads();

  if (oh == 0) {
    float acc[8];
#pragma unroll
    for (int j = 0; j < 8; j++) acc[j] = b_theta[j];
#pragma unroll 4
    for (int c = 0; c < 64; c++) {
      float xv = xs[c][t];
#pragma unroll
      for (int j = 0; j < 8; j++) acc[j] += xv * w_theta[j * 64 + c];
    }
    half8 h;
#pragma unroll
    for (int j = 0; j < 8; j++) h[j] = (_Float16)(acc[j] * LOG2E);
    *(half8*)(qf + ((size_t)b * NPIX + pr * 256 + t) * 8) = h;
  }

  int pos = t & 63;
  int ocg = t >> 6;
  int oc0 = oh * 36 + ocg * 9;
  const float* wrow[9];
  float a0[9], a1[9], a2[9], a3[9];
#pragma unroll
  for (int j = 0; j < 9; j++) {
    int oc = oc0 + j;
    float bv;
    if (oc < 64) { wrow[j] = w_g + oc * 64; bv = b_g[oc]; }
    else         { wrow[j] = w_phi + (oc - 64) * 64; bv = b_phi[oc - 64]; }
    a0[j] = bv; a1[j] = bv; a2[j] = bv; a3[j] = bv;
  }
#pragma unroll 4
  for (int c = 0; c < 64; c++) {
    float2 lo = *(const float2*)&xs[c][2 * pos];
    float2 hi = *(const float2*)&xs[c][128 + 2 * pos];
#pragma unroll
    for (int j = 0; j < 9; j++) {
      float wv = wrow[j][c];
      a0[j] += wv * lo.x;
      a1[j] += wv * lo.y;
      a2[j] += wv * hi.x;
      a3[j] += wv * hi.y;
    }
  }
  int m = pr * 64 + pos;
#pragma unroll
  for (int j = 0; j < 9; j++) {
    int oc = oc0 + j;
    float v = fmaxf(fmaxf(a0[j], a1[j]), fmaxf(a2[j], a3[j]));
    if (oc < 64) gT[((size_t)b * 64 + oc) * NPOOL + m] = (__bf16)v;
    else         phiT[((size_t)b * NPOOL + m) * 8 + (oc - 64)] = (_Float16)v;
  }
}

// ---- K2: flash attention; shift-free bf16-P softmax; gl_lds staging ----
// grid = b(2) x qt(128) x kc(8) = 2048 blocks; 4 waves x 32 queries
__global__ __launch_bounds__(256, 4) void attn_kernel(
    const _Float16* __restrict__ qf, const _Float16* __restrict__ phiT,
    const __bf16* __restrict__ gT,
    float* __restrict__ part_l, _Float16* __restrict__ part_o) {
  __shared__ __bf16 lds_g[2][128 * 64];  // double buffer, 16 KB each (128 keys)
  int bx = blockIdx.x;
  int kc = bx & (KSPLIT - 1);
  int qt = (bx >> 3) & 127;
  int b  = bx >> 10;
  int tid = threadIdx.x;
  int lane = tid & 63;
  int w = tid >> 6;
  int q = lane & 31, hi = lane >> 5;
  int qg0 = qt * 128 + w * 32;
  size_t qrow = (size_t)b * NPIX + qg0 + q;

  half8 qfrag = {0, 0, 0, 0, 0, 0, 0, 0};
  if (!hi) qfrag = *(const half8*)(qf + qrow * 8);

  f32x16 oacc0, oacc1, zero16;
#pragma unroll
  for (int i = 0; i < 16; i++) { oacc0[i] = 0.f; oacc1[i] = 0.f; zero16[i] = 0.f; }
  float lsum = 0.f;

  int kb0 = kc * CHUNK;

  // gl_lds staging: linear LDS dest (base + lane*16), inverse-swizzled source.
  const __bf16* gbase0;
  const __bf16* gbase1;
  {
    int c0 = (w * 2 + 0) * 8 + (lane >> 3);
    int c1 = (w * 2 + 1) * 8 + (lane >> 3);
    int s  = (lane & 7) ^ (lane >> 3);
    gbase0 = gT + ((size_t)b * 64 + c0) * NPOOL + 8 * s;
    gbase1 = gT + ((size_t)b * 64 + c1) * NPOOL + 8 * s;
  }
#define STAGE(buf, kb)                                                        \
  do {                                                                        \
    __builtin_amdgcn_global_load_lds(                                         \
        (const __attribute__((address_space(1))) void*)(gbase0 + (kb)),       \
        (__attribute__((address_space(3))) void*)((char*)&lds_g[buf][0] +     \
                                                  (w * 2 + 0) * 1024),        \
        16, 0, 0);                                                            \
    __builtin_amdgcn_global_load_lds(                                         \
        (const __attribute__((address_space(1))) void*)(gbase1 + (kb)),       \
        (__attribute__((address_space(3))) void*)((char*)&lds_g[buf][0] +     \
                                                  (w * 2 + 1) * 1024),        \
        16, 0, 0);                                                            \
    __builtin_amdgcn_global_load_lds(                                         \
        (const __attribute__((address_space(1))) void*)(gbase0 + (kb) + 64),  \
        (__attribute__((address_space(3))) void*)((char*)&lds_g[buf][0] +     \
                                                  8192 + (w * 2 + 0) * 1024), \
        16, 0, 0);                                                            \
    __builtin_amdgcn_global_load_lds(                                         \
        (const __attribute__((address_space(1))) void*)(gbase1 + (kb) + 64),  \
        (__attribute__((address_space(3))) void*)((char*)&lds_g[buf][0] +     \
                                                  8192 + (w * 2 + 1) * 1024), \
        16, 0, 0);                                                            \
  } while (0)

  STAGE(0, kb0);
  __syncthreads();                       // buf0 visible
  int cur = 0;

#pragma unroll 1
  for (int step = 0; step < NSTEP; ++step) {
    int kb = kb0 + step * 128;
    if (step + 1 < NSTEP) STAGE(cur ^ 1, kb + 128);  // prefetch next 128 keys
#pragma unroll
    for (int kk = 0; kk < 2; ++kk) {
      int kbb = kb + kk * 64;
      half8 aphi0 = {0, 0, 0, 0, 0, 0, 0, 0}, aphi1 = aphi0;
      if (!hi) {
        aphi0 = *(const half8*)(phiT + ((size_t)b * NPOOL + kbb + q) * 8);
        aphi1 = *(const half8*)(phiT + ((size_t)b * NPOOL + kbb + 32 + q) * 8);
      }
      const __bf16* ldsb = &lds_g[cur][kk * 4096];
#pragma unroll
      for (int sub = 0; sub < 2; ++sub) {
        half8 aphi = sub ? aphi1 : aphi0;
        f32x16 sacc = mfma16(aphi, qfrag, zero16);   // C-init from hoisted zeros
        float p[16];
#pragma unroll
        for (int i = 0; i < 16; i++) p[i] = fast_exp2(sacc[i]);
        lsum += (((p[0] + p[1]) + (p[2] + p[3])) + ((p[4] + p[5]) + (p[6] + p[7]))) +
                (((p[8] + p[9]) + (p[10] + p[11])) + ((p[12] + p[13]) + (p[14] + p[15])));
#pragma unroll
        for (int halfk = 0; halfk < 2; ++halfk) {
          int pb = halfk * 8;
          unsigned A0 = cvt_pk_bf16(p[pb + 0], p[pb + 1]);
          unsigned A1 = cvt_pk_bf16(p[pb + 2], p[pb + 3]);
          unsigned B0 = cvt_pk_bf16(p[pb + 4], p[pb + 5]);
          unsigned B1 = cvt_pk_bf16(p[pb + 6], p[pb + 7]);
          union { unsigned u[4]; bf16x8 h; } pf;
#if __has_builtin(__builtin_amdgcn_permlane32_swap)
          uint2v r0 = __builtin_amdgcn_permlane32_swap(A0, B0, false, false);
          uint2v r1 = __builtin_amdgcn_permlane32_swap(A1, B1, false, false);
          pf.u[0] = r0[0]; pf.u[1] = r1[0]; pf.u[2] = r0[1]; pf.u[3] = r1[1];
#else
          unsigned xA0 = __shfl_xor(A0, 32), xA1 = __shfl_xor(A1, 32);
          unsigned xB0 = __shfl_xor(B0, 32), xB1 = __shfl_xor(B1, 32);
          pf.u[0] = hi ? xB0 : A0;
          pf.u[1] = hi ? xB1 : A1;
          pf.u[2] = hi ? B0 : xA0;
          pf.u[3] = hi ? B1 : xA1;
#endif
          int sread = sub * 4 + halfk * 2 + hi;
          __builtin_amdgcn_s_setprio(1);
#pragma unroll
          for (int ct = 0; ct < 2; ++ct) {
            int row = ct * 32 + q;
            bf16x8 ag = *(const bf16x8*)(ldsb + row * 64 +
                                         (((16 * sread) ^ ((row & 7) << 4)) >> 1));
            if (ct == 0) oacc0 = mfma16b(ag, pf.h, oacc0);
            else         oacc1 = mfma16b(ag, pf.h, oacc1);
          }
          __builtin_amdgcn_s_setprio(0);
        }
      }
    }
    if (step + 1 < NSTEP) { __syncthreads(); cur ^= 1; }  // uniform condition
  }
  lsum += __shfl_xor(lsum, 32);          // chunk-total l (both half-lanes)
  float rl = 1.0f / lsum;
  if (!hi) part_l[(size_t)kc * BN + qrow] = lsum;
  // part_o f16 layout [kc][b][n][64] holds NORMALIZED o/l; 8B packed stores
  _Float16* po = part_o + (((size_t)(kc * 2 + b) * NPIX) + qg0 + q) * 64;
#pragma unroll
  for (int ct = 0; ct < 2; ++ct) {
#pragma unroll
    for (int g = 0; g < 4; ++g) {
      float v0 = (ct ? oacc1[4 * g + 0] : oacc0[4 * g + 0]) * rl;
      float v1 = (ct ? oacc1[4 * g + 1] : oacc0[4 * g + 1]) * rl;
      float v2 = (ct ? oacc1[4 * g + 2] : oacc0[4 * g + 2]) * rl;
      float v3 = (ct ? oacc1[4 * g + 3] : oacc0[4 * g + 3]) * rl;
      uint2v u;
      u[0] = __builtin_bit_cast(unsigned, __builtin_amdgcn_cvt_pkrtz(v0, v1));
      u[1] = __builtin_bit_cast(unsigned, __builtin_amdgcn_cvt_pkrtz(v2, v3));
      *(uint2v*)(po + 32 * ct + 8 * g + 4 * hi) = u;   // ch = (r&3)+8g+4hi+32ct
    }
  }
}

// ---- K3: l-weighted combine + residual epilogue ----
__global__ __launch_bounds__(256) void reduce_kernel(
    const float* __restrict__ part_l, const _Float16* __restrict__ part_o,
    const float* __restrict__ x, const float* __restrict__ sig,
    float* __restrict__ out) {
  int t = threadIdx.x;
  int cg = t >> 6;                       // 0..3 -> channels cg*16..+15
  int qi = blockIdx.x * 64 + (t & 63);
  int b = qi >> 14, n = qi & (NPIX - 1);
  float lv[KSPLIT], L = 0.f;
#pragma unroll
  for (int kc = 0; kc < KSPLIT; kc++) {
    lv[kc] = part_l[(size_t)kc * BN + qi];
    L += lv[kc];
  }
  float o16[16];
#pragma unroll
  for (int j = 0; j < 16; j++) o16[j] = 0.f;
#pragma unroll
  for (int kc = 0; kc < KSPLIT; kc++) {
    const _Float16* po = part_o + (((size_t)(kc * 2 + b) * NPIX) + n) * 64 + cg * 16;
    f16x8 v0 = *(const f16x8*)po;
    f16x8 v1 = *(const f16x8*)(po + 8);
    float wv = lv[kc];
#pragma unroll
    for (int j = 0; j < 8; j++) {
      o16[j]     += wv * (float)v0[j];
      o16[8 + j] += wv * (float)v1[j];
    }
  }
  float scale = sig[0] / L;
#pragma unroll
  for (int j = 0; j < 16; j++) {
    int c = cg * 16 + j;
    size_t idx = ((size_t)b * 64 + c) * NPIX + n;
    out[idx] = x[idx] + scale * o16[j];
  }
}

extern "C" void kernel_launch(void* const* d_in, const int* in_sizes, int n_in,
                              void* d_out, int out_size, void* d_ws, size_t ws_size,
                              hipStream_t stream) {
  const float* x       = (const float*)d_in[0];
  const float* w_theta = (const float*)d_in[1];
  const float* b_theta = (const float*)d_in[2];
  const float* w_phi   = (const float*)d_in[3];
  const float* b_phi   = (const float*)d_in[4];
  const float* w_g     = (const float*)d_in[5];
  const float* b_g     = (const float*)d_in[6];
  const float* sigma   = (const float*)d_in[7];
  float* out = (float*)d_out;

  // Workspace layout (bytes):
  //   qf     @ 0        : BN*8*2              = 524288
  //   phiT   @ 524288   : 2*NPOOL*8*2         = 131072
  //   gT     @ 655360   : 2*64*NPOOL*2        = 1048576  (bf16)
  //   part_l @ 1703936  : KSPLIT*BN*4         = 1048576
  //   part_o @ 2752512  : KSPLIT*2*NPIX*64*2  = 33554432   (total ~36.3 MB)
  char* ws = (char*)d_ws;
  _Float16* qf     = (_Float16*)ws;
  _Float16* phiT   = (_Float16*)(ws + 524288);
  __bf16*   gT     = (__bf16*)(ws + 655360);
  float*    part_l = (float*)(ws + 1703936);
  _Float16* part_o = (_Float16*)(ws + 2752512);

  prep_kernel<<<256, 256, 0, stream>>>(x, w_theta, b_theta, w_phi, b_phi,
                                       w_g, b_g, qf, phiT, gT);
  attn_kernel<<<2 * 128 * KSPLIT, 256, 0, stream>>>(qf, phiT, gT,
                                                    part_l, part_o);
  reduce_kernel<<<512, 256, 0, stream>>>(part_l, part_o, x, sigma, out);
}

// Round 20
// 61.629 us; speedup vs baseline: 1.6767x; 1.1035x over previous
//
#include <hip/hip_runtime.h>
#include <hip/hip_bf16.h>

typedef _Float16 half8 __attribute__((ext_vector_type(8)));
typedef _Float16 f16x8 __attribute__((ext_vector_type(8)));
typedef __bf16 bf16x8 __attribute__((ext_vector_type(8)));
typedef float f32x16 __attribute__((ext_vector_type(16)));
typedef unsigned uint2v __attribute__((ext_vector_type(2)));
typedef short short2v __attribute__((ext_vector_type(2)));

#define NPIX 16384      // H*W
#define NPOOL 4096      // pooled N
#define BN 32768        // B*N
#define KSPLIT 4
#define CHUNK 1024      // NPOOL/KSPLIT
#define NSTEP 8         // CHUNK/128 (128 keys per barrier frame)
#define LOG2E 1.44269504088896340736f

__device__ inline f32x16 mfma16(half8 a, half8 b, f32x16 c) {
  return __builtin_amdgcn_mfma_f32_32x32x16_f16(a, b, c, 0, 0, 0);
}
__device__ inline f32x16 mfma16b(bf16x8 a, bf16x8 b, f32x16 c) {
  return __builtin_amdgcn_mfma_f32_32x32x16_bf16(a, b, c, 0, 0, 0);
}
__device__ inline float fast_exp2(float x) {
#if __has_builtin(__builtin_amdgcn_exp2f)
  return __builtin_amdgcn_exp2f(x);      // raw v_exp_f32 (1 inst, <=1 ulp)
#else
  return exp2f(x);
#endif
}
// f32 pair -> packed 2x bf16 (RNE) in one instruction
__device__ inline unsigned cvt_pk_bf16(float lo, float hi) {
  unsigned r;
  asm("v_cvt_pk_bf16_f32 %0, %1, %2" : "=v"(r) : "v"(lo), "v"(hi));
  return r;
}
// lsum += bf16x2(u) . (1,1)  — uses packed P words (consistent with PV rounding)
__device__ inline float lsum_acc(unsigned u, float acc) {
#if __has_builtin(__builtin_amdgcn_fdot2_f32_bf16)
  const short2v ones = {(short)0x3F80, (short)0x3F80};  // bf16 1.0 x2
  return __builtin_amdgcn_fdot2_f32_bf16(__builtin_bit_cast(short2v, u), ones,
                                         acc, false);
#else
  unsigned lo = u << 16, hi = u & 0xFFFF0000u;
  return acc + __builtin_bit_cast(float, lo) + __builtin_bit_cast(float, hi);
#endif
}

// ---- K1 (fused prep): theta f16 [BN][8]*log2e; phiT f16 [b][M][8]; gT bf16 [b][64][M]
__global__ __launch_bounds__(256) void prep_kernel(
    const float* __restrict__ x,
    const float* __restrict__ w_theta, const float* __restrict__ b_theta,
    const float* __restrict__ w_phi, const float* __restrict__ b_phi,
    const float* __restrict__ w_g, const float* __restrict__ b_g,
    _Float16* __restrict__ qf, _Float16* __restrict__ phiT,
    __bf16* __restrict__ gT) {
  __shared__ float xs[64][256];
  int bid = blockIdx.x;
  int oh = bid & 1;
  int pr = (bid >> 1) & 63;
  int b  = bid >> 7;
  int t = threadIdx.x;

  const float* xb = x + (size_t)b * 64 * NPIX + pr * 256;
#pragma unroll 8
  for (int c = 0; c < 64; c++) xs[c][t] = xb[(size_t)c * NPIX + t];
  __syncthreads();

  if (oh == 0) {
    float acc[8];
#pragma unroll
    for (int j = 0; j < 8; j++) acc[j] = b_theta[j];
#pragma unroll 4
    for (int c = 0; c < 64; c++) {
      float xv = xs[c][t];
#pragma unroll
      for (int j = 0; j < 8; j++) acc[j] += xv * w_theta[j * 64 + c];
    }
    half8 h;
#pragma unroll
    for (int j = 0; j < 8; j++) h[j] = (_Float16)(acc[j] * LOG2E);
    *(half8*)(qf + ((size_t)b * NPIX + pr * 256 + t) * 8) = h;
  }

  int pos = t & 63;
  int ocg = t >> 6;
  int oc0 = oh * 36 + ocg * 9;
  const float* wrow[9];
  float a0[9], a1[9], a2[9], a3[9];
#pragma unroll
  for (int j = 0; j < 9; j++) {
    int oc = oc0 + j;
    float bv;
    if (oc < 64) { wrow[j] = w_g + oc * 64; bv = b_g[oc]; }
    else         { wrow[j] = w_phi + (oc - 64) * 64; bv = b_phi[oc - 64]; }
    a0[j] = bv; a1[j] = bv; a2[j] = bv; a3[j] = bv;
  }
#pragma unroll 4
  for (int c = 0; c < 64; c++) {
    float2 lo = *(const float2*)&xs[c][2 * pos];
    float2 hi = *(const float2*)&xs[c][128 + 2 * pos];
#pragma unroll
    for (int j = 0; j < 9; j++) {
      float wv = wrow[j][c];
      a0[j] += wv * lo.x;
      a1[j] += wv * lo.y;
      a2[j] += wv * hi.x;
      a3[j] += wv * hi.y;
    }
  }
  int m = pr * 64 + pos;
#pragma unroll
  for (int j = 0; j < 9; j++) {
    int oc = oc0 + j;
    float v = fmaxf(fmaxf(a0[j], a1[j]), fmaxf(a2[j], a3[j]));
    if (oc < 64) gT[((size_t)b * 64 + oc) * NPOOL + m] = (__bf16)v;
    else         phiT[((size_t)b * NPOOL + m) * 8 + (oc - 64)] = (_Float16)v;
  }
}

// ---- K2: flash attention; shift-free bf16-P softmax; gl_lds staging ----
// grid = b(2) x qt(128) x kc(4) = 1024 blocks; 4 waves x 32 queries
__global__ __launch_bounds__(256, 4) void attn_kernel(
    const _Float16* __restrict__ qf, const _Float16* __restrict__ phiT,
    const __bf16* __restrict__ gT,
    float* __restrict__ part_l, _Float16* __restrict__ part_o) {
  __shared__ __bf16 lds_g[2][128 * 64];  // double buffer, 16 KB each (128 keys)
  int bx = blockIdx.x;
  int kc = bx & (KSPLIT - 1);
  int qt = (bx >> 2) & 127;
  int b  = bx >> 9;
  int tid = threadIdx.x;
  int lane = tid & 63;
  int w = tid >> 6;
  int q = lane & 31, hi = lane >> 5;
  int qg0 = qt * 128 + w * 32;
  size_t qrow = (size_t)b * NPIX + qg0 + q;

  half8 qfrag = {0, 0, 0, 0, 0, 0, 0, 0};
  if (!hi) qfrag = *(const half8*)(qf + qrow * 8);

  f32x16 oacc0, oacc1, zero16;
#pragma unroll
  for (int i = 0; i < 16; i++) { oacc0[i] = 0.f; oacc1[i] = 0.f; zero16[i] = 0.f; }
  float lsum = 0.f;

  int kb0 = kc * CHUNK;

  // gl_lds staging: linear LDS dest (base + lane*16), inverse-swizzled source.
  const __bf16* gbase0;
  const __bf16* gbase1;
  {
    int c0 = (w * 2 + 0) * 8 + (lane >> 3);
    int c1 = (w * 2 + 1) * 8 + (lane >> 3);
    int s  = (lane & 7) ^ (lane >> 3);
    gbase0 = gT + ((size_t)b * 64 + c0) * NPOOL + 8 * s;
    gbase1 = gT + ((size_t)b * 64 + c1) * NPOOL + 8 * s;
  }
#define STAGE(buf, kb)                                                        \
  do {                                                                        \
    __builtin_amdgcn_global_load_lds(                                         \
        (const __attribute__((address_space(1))) void*)(gbase0 + (kb)),       \
        (__attribute__((address_space(3))) void*)((char*)&lds_g[buf][0] +     \
                                                  (w * 2 + 0) * 1024),        \
        16, 0, 0);                                                            \
    __builtin_amdgcn_global_load_lds(                                         \
        (const __attribute__((address_space(1))) void*)(gbase1 + (kb)),       \
        (__attribute__((address_space(3))) void*)((char*)&lds_g[buf][0] +     \
                                                  (w * 2 + 1) * 1024),        \
        16, 0, 0);                                                            \
    __builtin_amdgcn_global_load_lds(                                         \
        (const __attribute__((address_space(1))) void*)(gbase0 + (kb) + 64),  \
        (__attribute__((address_space(3))) void*)((char*)&lds_g[buf][0] +     \
                                                  8192 + (w * 2 + 0) * 1024), \
        16, 0, 0);                                                            \
    __builtin_amdgcn_global_load_lds(                                         \
        (const __attribute__((address_space(1))) void*)(gbase1 + (kb) + 64),  \
        (__attribute__((address_space(3))) void*)((char*)&lds_g[buf][0] +     \
                                                  8192 + (w * 2 + 1) * 1024), \
        16, 0, 0);                                                            \
  } while (0)

  STAGE(0, kb0);
  __syncthreads();                       // buf0 visible
  int cur = 0;

#pragma unroll 1
  for (int step = 0; step < NSTEP; ++step) {
    int kb = kb0 + step * 128;
    if (step + 1 < NSTEP) STAGE(cur ^ 1, kb + 128);  // prefetch next 128 keys
#pragma unroll
    for (int kk = 0; kk < 2; ++kk) {
      int kbb = kb + kk * 64;
      half8 aphi0 = {0, 0, 0, 0, 0, 0, 0, 0}, aphi1 = aphi0;
      if (!hi) {
        aphi0 = *(const half8*)(phiT + ((size_t)b * NPOOL + kbb + q) * 8);
        aphi1 = *(const half8*)(phiT + ((size_t)b * NPOOL + kbb + 32 + q) * 8);
      }
      const __bf16* ldsb = &lds_g[cur][kk * 4096];
#pragma unroll
      for (int sub = 0; sub < 2; ++sub) {
        half8 aphi = sub ? aphi1 : aphi0;
        f32x16 sacc = mfma16(aphi, qfrag, zero16);   // C-init from hoisted zeros
        float p[16];
#pragma unroll
        for (int i = 0; i < 16; i++) p[i] = fast_exp2(sacc[i]);
#pragma unroll
        for (int halfk = 0; halfk < 2; ++halfk) {
          int pb = halfk * 8;
          unsigned A0 = cvt_pk_bf16(p[pb + 0], p[pb + 1]);
          unsigned A1 = cvt_pk_bf16(p[pb + 2], p[pb + 3]);
          unsigned B0 = cvt_pk_bf16(p[pb + 4], p[pb + 5]);
          unsigned B1 = cvt_pk_bf16(p[pb + 6], p[pb + 7]);
          lsum = lsum_acc(A0, lsum);
          lsum = lsum_acc(A1, lsum);
          lsum = lsum_acc(B0, lsum);
          lsum = lsum_acc(B1, lsum);
          union { unsigned u[4]; bf16x8 h; } pf;
#if __has_builtin(__builtin_amdgcn_permlane32_swap)
          uint2v r0 = __builtin_amdgcn_permlane32_swap(A0, B0, false, false);
          uint2v r1 = __builtin_amdgcn_permlane32_swap(A1, B1, false, false);
          pf.u[0] = r0[0]; pf.u[1] = r1[0]; pf.u[2] = r0[1]; pf.u[3] = r1[1];
#else
          unsigned xA0 = __shfl_xor(A0, 32), xA1 = __shfl_xor(A1, 32);
          unsigned xB0 = __shfl_xor(B0, 32), xB1 = __shfl_xor(B1, 32);
          pf.u[0] = hi ? xB0 : A0;
          pf.u[1] = hi ? xB1 : A1;
          pf.u[2] = hi ? B0 : xA0;
          pf.u[3] = hi ? B1 : xA1;
#endif
          int sread = sub * 4 + halfk * 2 + hi;
          __builtin_amdgcn_s_setprio(1);
#pragma unroll
          for (int ct = 0; ct < 2; ++ct) {
            int row = ct * 32 + q;
            bf16x8 ag = *(const bf16x8*)(ldsb + row * 64 +
                                         (((16 * sread) ^ ((row & 7) << 4)) >> 1));
            if (ct == 0) oacc0 = mfma16b(ag, pf.h, oacc0);
            else         oacc1 = mfma16b(ag, pf.h, oacc1);
          }
          __builtin_amdgcn_s_setprio(0);
        }
      }
    }
    if (step + 1 < NSTEP) { __syncthreads(); cur ^= 1; }  // uniform condition
  }
  lsum += __shfl_xor(lsum, 32);          // chunk-total l (both half-lanes)
  float rl = 1.0f / lsum;
  if (!hi) part_l[(size_t)kc * BN + qrow] = lsum;
  // part_o f16 layout [kc][b][n][64] holds NORMALIZED o/l; 8B packed stores
  _Float16* po = part_o + (((size_t)(kc * 2 + b) * NPIX) + qg0 + q) * 64;
#pragma unroll
  for (int ct = 0; ct < 2; ++ct) {
#pragma unroll
    for (int g = 0; g < 4; ++g) {
      float v0 = (ct ? oacc1[4 * g + 0] : oacc0[4 * g + 0]) * rl;
      float v1 = (ct ? oacc1[4 * g + 1] : oacc0[4 * g + 1]) * rl;
      float v2 = (ct ? oacc1[4 * g + 2] : oacc0[4 * g + 2]) * rl;
      float v3 = (ct ? oacc1[4 * g + 3] : oacc0[4 * g + 3]) * rl;
      uint2v u;
      u[0] = __builtin_bit_cast(unsigned, __builtin_amdgcn_cvt_pkrtz(v0, v1));
      u[1] = __builtin_bit_cast(unsigned, __builtin_amdgcn_cvt_pkrtz(v2, v3));
      *(uint2v*)(po + 32 * ct + 8 * g + 4 * hi) = u;   // ch = (r&3)+8g+4hi+32ct
    }
  }
}

// ---- K3: l-weighted combine + residual epilogue ----
__global__ __launch_bounds__(256) void reduce_kernel(
    const float* __restrict__ part_l, const _Float16* __restrict__ part_o,
    const float* __restrict__ x, const float* __restrict__ sig,
    float* __restrict__ out) {
  int t = threadIdx.x;
  int cg = t >> 6;                       // 0..3 -> channels cg*16..+15
  int qi = blockIdx.x * 64 + (t & 63);
  int b = qi >> 14, n = qi & (NPIX - 1);
  float lv[KSPLIT], L = 0.f;
#pragma unroll
  for (int kc = 0; kc < KSPLIT; kc++) {
    lv[kc] = part_l[(size_t)kc * BN + qi];
    L += lv[kc];
  }
  float o16[16];
#pragma unroll
  for (int j = 0; j < 16; j++) o16[j] = 0.f;
#pragma unroll
  for (int kc = 0; kc < KSPLIT; kc++) {
    const _Float16* po = part_o + (((size_t)(kc * 2 + b) * NPIX) + n) * 64 + cg * 16;
    f16x8 v0 = *(const f16x8*)po;
    f16x8 v1 = *(const f16x8*)(po + 8);
    float wv = lv[kc];
#pragma unroll
    for (int j = 0; j < 8; j++) {
      o16[j]     += wv * (float)v0[j];
      o16[8 + j] += wv * (float)v1[j];
    }
  }
  float scale = sig[0] / L;
#pragma unroll
  for (int j = 0; j < 16; j++) {
    int c = cg * 16 + j;
    size_t idx = ((size_t)b * 64 + c) * NPIX + n;
    out[idx] = x[idx] + scale * o16[j];
  }
}

extern "C" void kernel_launch(void* const* d_in, const int* in_sizes, int n_in,
                              void* d_out, int out_size, void* d_ws, size_t ws_size,
                              hipStream_t stream) {
  const float* x       = (const float*)d_in[0];
  const float* w_theta = (const float*)d_in[1];
  const float* b_theta = (const float*)d_in[2];
  const float* w_phi   = (const float*)d_in[3];
  const float* b_phi   = (const float*)d_in[4];
  const float* w_g     = (const float*)d_in[5];
  const float* b_g     = (const float*)d_in[6];
  const float* sigma   = (const float*)d_in[7];
  float* out = (float*)d_out;

  // Workspace layout (bytes):
  //   qf     @ 0        : BN*8*2              = 524288
  //   phiT   @ 524288   : 2*NPOOL*8*2         = 131072
  //   gT     @ 655360   : 2*64*NPOOL*2        = 1048576  (bf16)
  //   part_l @ 1703936  : KSPLIT*BN*4         = 524288
  //   part_o @ 2228224  : KSPLIT*2*NPIX*64*2  = 16777216   (total ~19 MB)
  char* ws = (char*)d_ws;
  _Float16* qf     = (_Float16*)ws;
  _Float16* phiT   = (_Float16*)(ws + 524288);
  __bf16*   gT     = (__bf16*)(ws + 655360);
  float*    part_l = (float*)(ws + 1703936);
  _Float16* part_o = (_Float16*)(ws + 2228224);

  prep_kernel<<<256, 256, 0, stream>>>(x, w_theta, b_theta, w_phi, b_phi,
                                       w_g, b_g, qf, phiT, gT);
  attn_kernel<<<2 * 128 * KSPLIT, 256, 0, stream>>>(qf, phiT, gT,
                                                    part_l, part_o);
  reduce_kernel<<<512, 256, 0, stream>>>(part_l, part_o, x, sigma, out);
}